// Round 4
// baseline (68.098 us; speedup 1.0000x reference)
//
#include <hip/hip_runtime.h>
#include <hip/hip_bf16.h>

// Problem: B=512, S=256, E=384, H=64.
// d_in: x [B,S,E] f32; Wq,Wk,Wv [E,H] f32.  d_out: [B,S,H] f32.
// ws: [0, 147456) wfrag bf16; [262144, +16.8MB) q bf16 [B][S][64].
//
// FUSED v4: one block per batch, 384 threads (6 waves), LDS 77.8 KB
// -> 2 blocks/CU = 12 waves/CU (v2 had 8; scaling law 4w:115us -> 8w:57us).
// Q bypasses LDS entirely (global ws, L2-hot round trip) so proj VGPR
// stays under the 170 cap for 3 waves/SIMD. K,V stay in LDS (swizzled).
// Attention: v3's verified swapped-QK in-lane-P mapping, 1-pass softmax
// (s[16] in regs, fully static indexing), balanced causal tile partition.

#define NB   512
#define SS   256
#define EE   384
#define HH   64

typedef short bf16x8 __attribute__((ext_vector_type(8)));
typedef float f32x4  __attribute__((ext_vector_type(4)));

__device__ __forceinline__ short f2bf(float f) {
  union { float f; unsigned u; } x; x.f = f;
  unsigned r = x.u + 0x7fffu + ((x.u >> 16) & 1u);
  return (short)(r >> 16);
}

// ---------------- prep: W -> fragment-ordered bf16 (unchanged) ----------------
// wfrag[((ks*12+nf)*64 + lane)*8 + j] = Wcat[ks*32 + (lane>>4)*8 + j][nf*16 + (lane&15)]
__global__ __launch_bounds__(256) void prep_w_kernel(
    const float* __restrict__ Wq, const float* __restrict__ Wk,
    const float* __restrict__ Wv, short* __restrict__ wfrag) {
  int t = blockIdx.x * 256 + threadIdx.x;
  if (t >= 12 * 12 * 64) return;
  int ks  = t / (12 * 64);
  int rem = t % (12 * 64);
  int nf  = rem / 64;
  int l   = rem % 64;
  int l15 = l & 15, lhi = l >> 4;
  int ncat = nf * 16 + l15;
  const float* W = (ncat < 64) ? Wq : (ncat < 128 ? Wk : Wv);
  int n = ncat & 63;
  short* dst = wfrag + (size_t)t * 8;
#pragma unroll
  for (int j = 0; j < 8; ++j) {
    int kk = ks * 32 + lhi * 8 + j;
    dst[j] = f2bf(W[kk * 64 + n]);
  }
}

// ---------------- fused: one block = one batch, 6 waves, 77.8 KB LDS ----------------
__global__ __launch_bounds__(384, 3) void fused_kernel(
    const float* __restrict__ x, const short* __restrict__ wfrag,
    short* __restrict__ qws, float* __restrict__ out) {
  // K swizzled: elem (row,h) at Kl[row*64 + (h ^ (srow<<3))], srow=((row&8)>>1)|(row&3)
  // V^T swizzled: elem (h,row) at Vt[h*256 + (row ^ ((h&7)<<3))]
  // x stage: 16 rows x 384 bf16; 16B chunk c8 of row r stored at (c8 ^ (r&7))
  __shared__ __align__(16) short Kl[SS * HH];   // 32 KB
  __shared__ __align__(16) short Vt[HH * SS];   // 32 KB
  __shared__ __align__(16) short xst[16 * EE];  // 12 KB  -> 77824 B total

  int b    = blockIdx.x;
  int tid  = threadIdx.x;
  int lane = tid & 63, wv = tid >> 6;           // wv in [0,6)
  int l15  = lane & 15, lhi = lane >> 4;
  int sw   = l15 & 7;
  const float* xb = x + (size_t)b * SS * EE;
  short* qbb = qws + (size_t)b * SS * HH;

  // ---- W fragments resident: exactly 2 h-tiles/wave (f = wv*2+ht), 96 VGPR ----
  bf16x8 af[12][2];
#pragma unroll
  for (int ks = 0; ks < 12; ++ks)
#pragma unroll
    for (int ht = 0; ht < 2; ++ht)
      af[ks][ht] = *(const bf16x8*)(wfrag + ((size_t)(ks * 12 + wv * 2 + ht) * 64 + lane) * 8);

  f32x4 st[4];
  auto loadch = [&](int ch) {  // 16 rows = 24 KB f32, fully contiguous, 64 B/thread
    const float* p0 = xb + (size_t)ch * 16 * EE;
#pragma unroll
    for (int i = 0; i < 4; ++i)
      st[i] = *(const f32x4*)(p0 + (size_t)(tid + 384 * i) * 4);
  };
  auto writech = [&]() {  // regs -> bf16 -> swizzled LDS (8 B stores)
#pragma unroll
    for (int i = 0; i < 4; ++i) {
      int c16 = tid + 384 * i;       // 16B-f32 chunk: row = c16/96, cg4 = c16%96
      int row = c16 / 96, cg4 = c16 % 96;
      union { short4 s4; __hip_bfloat162 h2[2]; } u;
      u.h2[0] = __float22bfloat162_rn(make_float2(st[i][0], st[i][1]));
      u.h2[1] = __float22bfloat162_rn(make_float2(st[i][2], st[i][3]));
      *(short4*)(xst + row * 384 + (((cg4 >> 1) ^ (row & 7)) * 8 + (cg4 & 1) * 4)) = u.s4;
    }
  };

  // ---- projection: 16 chunks of 16 rows, reg-prefetched, single LDS buffer ----
  loadch(0);
  writech();
  for (int ch = 0; ch < 16; ++ch) {
    __syncthreads();                 // xst(ch) visible
    if (ch < 15) loadch(ch + 1);     // issue next chunk's global loads

    f32x4 acc[2];
    acc[0] = (f32x4){0.f, 0.f, 0.f, 0.f};
    acc[1] = (f32x4){0.f, 0.f, 0.f, 0.f};
#pragma unroll
    for (int ks = 0; ks < 12; ++ks) {
      bf16x8 bx = *(const bf16x8*)(xst + l15 * 384 + (((ks * 4 + lhi) ^ sw) * 8));
      acc[0] = __builtin_amdgcn_mfma_f32_16x16x32_bf16(af[ks][0], bx, acc[0], 0, 0, 0);
      acc[1] = __builtin_amdgcn_mfma_f32_16x16x32_bf16(af[ks][1], bx, acc[1], 0, 0, 0);
    }

    // epilogue: f = wv*2+ht (wave-uniform class), ncat = f*16+lhi*4, row = ch*16+l15
    int row  = ch * 16 + l15;
    int srow = ((row & 8) >> 1) | (row & 3);
#pragma unroll
    for (int ht = 0; ht < 2; ++ht) {
      int f = wv * 2 + ht;
      int ncat = f * 16 + lhi * 4;
      if (f < 4) {          // Q -> global ws, row-major (L2-hot, read back in attn)
        union { short4 s4; __hip_bfloat162 h2[2]; } oq;
        oq.h2[0] = __float22bfloat162_rn(make_float2(acc[ht][0], acc[ht][1]));
        oq.h2[1] = __float22bfloat162_rn(make_float2(acc[ht][2], acc[ht][3]));
        *(short4*)(qbb + (size_t)row * HH + ncat) = oq.s4;
      } else if (f < 8) {   // K -> Kl swizzled
        int col = ncat - 64;
        union { short4 s4; __hip_bfloat162 h2[2]; } ok;
        ok.h2[0] = __float22bfloat162_rn(make_float2(acc[ht][0], acc[ht][1]));
        ok.h2[1] = __float22bfloat162_rn(make_float2(acc[ht][2], acc[ht][3]));
        *(short4*)(Kl + row * 64 + (col ^ (srow << 3))) = ok.s4;
      } else {              // V -> Vt transposed, scalar stores
#pragma unroll
        for (int j = 0; j < 4; ++j) {
          int h = ncat - 128 + j;
          Vt[h * 256 + (row ^ ((h & 7) << 3))] = f2bf(acc[ht][j]);
        }
      }
    }
    __syncthreads();                 // reads of xst(ch) done
    if (ch < 15) writech();          // overwrite stage with chunk ch+1
  }
  __syncthreads();                   // Kl/Vt complete; Q stores drained to L2

  // ---- attention: balanced causal partition, in-lane P, 1-pass softmax ----
  // tiles per wave: w0{13,5,2} w1{12,4,3} w2{11,8,0} w3{10,9,1} w4{15,6} w5{14,7}
  size_t obase = (size_t)b * SS * HH;
#pragma unroll
  for (int u = 0; u < 3; ++u) {
    if (u == 2 && wv >= 4) continue;     // wave-uniform
    int rt;
    if (u == 0)      rt = (wv < 4) ? (13 - wv) : (19 - wv);
    else if (u == 1) rt = (wv < 2) ? (5 - wv) : ((wv < 4) ? (6 + wv) : (2 + wv));
    else             rt = (wv < 2) ? (2 + wv) : (wv - 2);

    int qrow0 = rt * 16;
    int twp   = (rt + 2) & ~1;           // even # of interleaved 16-row k-tiles
    int nk    = twp >> 1;                // 32-k PV chunks
    int qg    = qrow0 + l15;             // this lane's q-row (P lives at q=l15)

    // Q fragments: direct vector loads from L2-hot ws (row-major, no swizzle)
    const short* qrow = qbb + (size_t)(qrow0 + l15) * HH;
    bf16x8 qa0 = *(const bf16x8*)(qrow + lhi * 8);
    bf16x8 qa1 = *(const bf16x8*)(qrow + 32 + lhi * 8);

    // scores: tile t loads K rows kc = (t>>1)*32 + (l15>>2)*8 + (t&1)*4 + (l15&3)
    // (interleaved mapping makes srow(kc) == sw, and D-layout == PV A-fragment)
    f32x4 s[16];
#pragma unroll
    for (int t = 0; t < 16; ++t) {
      if (t >= twp) continue;
      int kc = (t >> 1) * 32 + ((l15 >> 2) << 3) + ((t & 1) << 2) + (l15 & 3);
      const short* kp = Kl + kc * 64;
      bf16x8 kb0 = *(const bf16x8*)(kp + ((lhi * 8) ^ (sw << 3)));
      bf16x8 kb1 = *(const bf16x8*)(kp + ((32 + lhi * 8) ^ (sw << 3)));
      f32x4 a = (f32x4){0.f, 0.f, 0.f, 0.f};
      a = __builtin_amdgcn_mfma_f32_16x16x32_bf16(kb0, qa0, a, 0, 0, 0);
      a = __builtin_amdgcn_mfma_f32_16x16x32_bf16(kb1, qa1, a, 0, 0, 0);
#pragma unroll
      for (int r = 0; r < 4; ++r) {
        int kg = (t >> 1) * 32 + lhi * 8 + ((t & 1) << 2) + r;
        s[t][r] = (kg <= qg) ? a[r] * 0.125f : -INFINITY;
      }
    }

    // softmax over lane-local row (q=l15), reduce across lhi groups
    float mx = -3.0e38f;
#pragma unroll
    for (int t = 0; t < 16; ++t) {
      if (t >= twp) continue;
#pragma unroll
      for (int r = 0; r < 4; ++r) mx = fmaxf(mx, s[t][r]);
    }
    mx = fmaxf(mx, __shfl_xor(mx, 16));
    mx = fmaxf(mx, __shfl_xor(mx, 32));
    float sm = 0.f;
#pragma unroll
    for (int t = 0; t < 16; ++t) {
      if (t >= twp) continue;
#pragma unroll
      for (int r = 0; r < 4; ++r) {
        float p = __expf(s[t][r] - mx);    // exp(-inf)=0
        s[t][r] = p;
        sm += p;
      }
    }
    sm += __shfl_xor(sm, 16);
    sm += __shfl_xor(sm, 32);
    float inv = 1.f / sm;
    float invq[4];
#pragma unroll
    for (int r = 0; r < 4; ++r) invq[r] = __shfl(inv, lhi * 4 + r);

    // PV: pack P in-lane (no LDS), accumulate
    f32x4 o[4];
#pragma unroll
    for (int nf = 0; nf < 4; ++nf) o[nf] = (f32x4){0.f, 0.f, 0.f, 0.f};
#pragma unroll
    for (int kc2 = 0; kc2 < 8; ++kc2) {
      if (kc2 >= nk) continue;
      union { bf16x8 v; __hip_bfloat162 h2[4]; } pu;
      pu.h2[0] = __float22bfloat162_rn(make_float2(s[2*kc2][0],   s[2*kc2][1]));
      pu.h2[1] = __float22bfloat162_rn(make_float2(s[2*kc2][2],   s[2*kc2][3]));
      pu.h2[2] = __float22bfloat162_rn(make_float2(s[2*kc2+1][0], s[2*kc2+1][1]));
      pu.h2[3] = __float22bfloat162_rn(make_float2(s[2*kc2+1][2], s[2*kc2+1][3]));
      int kofs = kc2 * 32 + lhi * 8;
#pragma unroll
      for (int nf = 0; nf < 4; ++nf) {
        int hrow = nf * 16 + l15;
        bf16x8 vb = *(const bf16x8*)(Vt + hrow * 256 + (kofs ^ ((hrow & 7) << 3)));
        o[nf] = __builtin_amdgcn_mfma_f32_16x16x32_bf16(pu.v, vb, o[nf], 0, 0, 0);
      }
    }

    // store (divide by row sum here)
#pragma unroll
    for (int nf = 0; nf < 4; ++nf)
#pragma unroll
      for (int r = 0; r < 4; ++r) {
        int q = qrow0 + lhi * 4 + r;
        int h = nf * 16 + l15;
        out[obase + (size_t)q * HH + h] = o[nf][r] * invq[r];
      }
  }
}

extern "C" void kernel_launch(void* const* d_in, const int* in_sizes, int n_in,
                              void* d_out, int out_size, void* d_ws, size_t ws_size,
                              hipStream_t stream) {
  const float* x  = (const float*)d_in[0];
  const float* Wq = (const float*)d_in[1];
  const float* Wk = (const float*)d_in[2];
  const float* Wv = (const float*)d_in[3];
  float* out = (float*)d_out;

  char* ws = (char*)d_ws;
  short* wfrag = (short*)ws;
  short* qws   = (short*)(ws + 262144);

  prep_w_kernel<<<36, 256, 0, stream>>>(Wq, Wk, Wv, wfrag);
  fused_kernel<<<512, 384, 0, stream>>>(x, wfrag, qws, out);
}